// Round 6
// baseline (352.132 us; speedup 1.0000x reference)
//
#include <hip/hip_runtime.h>

// DDLG autoencoder, SINGLE dispatch, persistent 2-tile blocks, batch-tile 4,
// ALL-fp16 packed compute.
//   out[b][o] = sum_f prob[o][f] * op_f(x[b][idx[o][0..7]])
// R1: divide-free Einstein reductions via homomorphisms:
//     ein-product = 2D/(N+D),  D=prod(f), N=prod(2-f)
//     ein-sum     = (N-D)/(N+D), N=prod(1+f), D=prod(1-f)
// R8: combined-denominator finale (one rcp pair per h2 over s1*s2; range
//     proof: s1*s2 <= 2.25^8 + 257 ~ 914 < 65504, numerators <= 912).
// R9: chain+finale in explicit 2-wide _Float16 (native v_pk_*_f16 width).
// R12 (this round) -- R5 showed 32 lock-stepped waves beat 24 decoupled ones;
//     revert to the measured-best residency (1024 thr, 48 KB, 2 blocks/CU)
//     and attack the remaining exposed phase: block-start x staging.
//   - persistent 2-tile blocks (grid 512): tile1's x is float4-loaded during
//     tile0's L1 phase (latency fully covered by L1 gates), packed to 8 VGPRs,
//     ds-written into the x buffer at L3 start (buffer dead after L2).
//     Tile1 starts compute with x resident: its staging head vanishes.
//   - float4 x staging: 4x global_load_dwordx4 + 2x ds_write_b128 per thread
//     (was 16 scalar dwords + 4 b64 writes).
//   - inline NO-MAX softmax per gate (w~N(0,1): exp(w) fp32-safe; identical
//     math to normalized softmax within fp32 rounding). Single dispatch,
//     no prep kernel, no workspace.
//     LDS overlays (fp16 rows of 4 = 8 B, ds_read_b64 gathers):
//       A: x @ [0,16384) elems | C: h0/h2 @ [16384,24576) | h1 over dead A[0,4096)

typedef _Float16 h2 __attribute__((ext_vector_type(2)));

__device__ __forceinline__ float fastrcp(float x) { return __builtin_amdgcn_rcpf(x); }
__device__ __forceinline__ _Float16 hrcp(_Float16 x) {
#if __has_builtin(__builtin_amdgcn_rcph)
    return __builtin_amdgcn_rcph(x);
#else
    return (_Float16)__builtin_amdgcn_rcpf((float)x);
#endif
}
__device__ __forceinline__ h2 splat2(_Float16 s) { h2 v = {s, s}; return v; }
__device__ __forceinline__ unsigned packh2(float a, float b) {
    h2 v = {(_Float16)a, (_Float16)b};
    return __builtin_bit_cast(unsigned, v);
}

// ---------------- inline per-gate softmax (no max-sub: w ~ N(0,1), fp32-safe) ---
__device__ __forceinline__ void probs_of(const float* __restrict__ w, int o,
                                         bool train, _Float16 P[4]) {
    const float4 wv = ((const float4*)w)[o];
    if (train) {
        float e0 = __expf(wv.x), e1 = __expf(wv.y);
        float e2 = __expf(wv.z), e3 = __expf(wv.w);
        float inv = fastrcp(e0 + e1 + e2 + e3);
        P[0] = (_Float16)(e0 * inv); P[1] = (_Float16)(e1 * inv);
        P[2] = (_Float16)(e2 * inv); P[3] = (_Float16)(e3 * inv);
    } else {
        // first-max argmax (matches jnp.argmax one_hot semantics)
        int a = 0; float best = wv.x;
        if (wv.y > best) { best = wv.y; a = 1; }
        if (wv.z > best) { best = wv.z; a = 2; }
        if (wv.w > best) { best = wv.w; a = 3; }
        P[0] = (_Float16)(a == 0 ? 1.0f : 0.0f);
        P[1] = (_Float16)(a == 1 ? 1.0f : 0.0f);
        P[2] = (_Float16)(a == 2 ? 1.0f : 0.0f);
        P[3] = (_Float16)(a == 3 ? 1.0f : 0.0f);
    }
}

// ---------------- one LDS row = 4 fp16 (batch lanes 0..3) as 2x h2 ----------------
struct Raw { h2 lo, hi; };

__device__ __forceinline__ Raw row_at(const uint2* __restrict__ rows, int i) {
    const uint2 v = rows[i];                 // one ds_read_b64
    Raw r;
    r.lo = __builtin_bit_cast(h2, v.x);
    r.hi = __builtin_bit_cast(h2, v.y);
    return r;
}
__device__ __forceinline__ uint2 raw_bits(Raw r) {
    return uint2{__builtin_bit_cast(unsigned, r.lo), __builtin_bit_cast(unsigned, r.hi)};
}

// ---------------- chain state: 6 parallel reductions x 2 halves ----------------
struct Chain { h2 mn0, mn1, mx0, mx1, De0, De1, Ne0, Ne1, Nc0, Nc1, Dc0, Dc1; };

__device__ __forceinline__ void cinit(Chain& C, Raw v) {
    const h2 one = splat2((_Float16)1.0f), two = splat2((_Float16)2.0f);
    C.mn0 = v.lo; C.mx0 = v.lo; C.De0 = v.lo;
    C.Ne0 = two - v.lo; C.Nc0 = one + v.lo; C.Dc0 = one - v.lo;
    C.mn1 = v.hi; C.mx1 = v.hi; C.De1 = v.hi;
    C.Ne1 = two - v.hi; C.Nc1 = one + v.hi; C.Dc1 = one - v.hi;
}
__device__ __forceinline__ void cstep(Chain& C, Raw v) {
    const h2 two = splat2((_Float16)2.0f);
    C.mn0 = __builtin_elementwise_min(C.mn0, v.lo);
    C.mn1 = __builtin_elementwise_min(C.mn1, v.hi);
    C.mx0 = __builtin_elementwise_max(C.mx0, v.lo);
    C.mx1 = __builtin_elementwise_max(C.mx1, v.hi);
    C.De0 *= v.lo;            C.De1 *= v.hi;
    C.Ne0 *= (two - v.lo);    C.Ne1 *= (two - v.hi);
    C.Nc0 += C.Nc0 * v.lo;    C.Nc1 += C.Nc1 * v.hi;   // pk_fma: Nc *= (1+v)
    C.Dc0 -= C.Dc0 * v.lo;    C.Dc1 -= C.Dc1 * v.hi;   // pk_fma: Dc *= (1-v)
}
// combined-denominator finale: one rcp pair per half serves both ein and coe.
__device__ __forceinline__ Raw finale(const Chain& C, const _Float16 P[4]) {
    h2 s10 = C.Ne0 + C.De0, s11 = C.Ne1 + C.De1;   // [1, 257]
    h2 s20 = C.Nc0 + C.Dc0, s21 = C.Nc1 + C.Dc1;   // [1, 257]
    h2 d10 = C.Nc0 - C.Dc0, d11 = C.Nc1 - C.Dc1;   // [0, 256]
    h2 ss0 = s10 * s20,     ss1 = s11 * s21;       // <= ~914: fp16-safe
    h2 r0 = {hrcp(ss0[0]), hrcp(ss0[1])};
    h2 r1 = {hrcp(ss1[0]), hrcp(ss1[1])};
    h2 t10 = (C.De0 + C.De0) * s20, t11 = (C.De1 + C.De1) * s21;  // <= 514
    h2 t20 = d10 * s10,             t21 = d11 * s11;              // <= 912
    const h2 P0 = splat2(P[0]), P1 = splat2(P[1]);
    const h2 P2 = splat2(P[2]), P3 = splat2(P[3]);
    h2 num0 = P2 * t10 + P3 * t20;
    h2 num1 = P2 * t11 + P3 * t21;
    Raw res;
    res.lo = P0 * C.mn0 + P1 * C.mx0 + num0 * r0;
    res.hi = P0 * C.mn1 + P1 * C.mx1 + num1 * r1;
    return res;
}

// ---------------- one gate, 4 batch lanes, inline probs ----------------
__device__ __forceinline__ Raw gate(const uint2* __restrict__ rows,
                                    const int4* __restrict__ idx,
                                    const float* __restrict__ w,
                                    bool train, int o) {
    const int4 i0 = idx[o * 2], i1 = idx[o * 2 + 1];
    _Float16 P[4];
    probs_of(w, o, train, P);
    Raw A[8];
    A[0] = row_at(rows, i0.x); A[1] = row_at(rows, i0.y);
    A[2] = row_at(rows, i0.z); A[3] = row_at(rows, i0.w);
    A[4] = row_at(rows, i1.x); A[5] = row_at(rows, i1.y);
    A[6] = row_at(rows, i1.z); A[7] = row_at(rows, i1.w);
    Chain C; cinit(C, A[0]);
#pragma unroll
    for (int c = 1; c < 8; ++c) cstep(C, A[c]);
    return finale(C, P);
}

// ---------------- the fused network ----------------
// grid = 512 persistent blocks, each does 2 batch tiles of 4; block = 1024,
// 48 KB LDS -> 2 blocks/CU (32 waves, wave-slot-limited). VGPR must be <=64.
__global__ __launch_bounds__(1024, 8) void ddlg_fused(const float* __restrict__ x,
                                                      const float* __restrict__ w0,
                                                      const float* __restrict__ w1,
                                                      const float* __restrict__ w2,
                                                      const float* __restrict__ w3,
                                                      const int* __restrict__ is_train,
                                                      const int4* __restrict__ idx0,
                                                      const int4* __restrict__ idx1,
                                                      const int4* __restrict__ idx2,
                                                      const int4* __restrict__ idx3,
                                                      float* __restrict__ out) {
    __shared__ __align__(16) _Float16 lds[24576];   // 48 KB
    const int t  = threadIdx.x;
    const int b0 = blockIdx.x << 3;                 // 8 batch rows: tiles b0, b0+4
    const bool train = (*is_train) != 0;
    const int j0 = t << 2;                          // this thread's 4 staging rows

    const uint2* xl  = (const uint2*)lds;            // rows [0,4096)
    const uint2* h0v = (const uint2*)(lds + 16384);  // rows [0,2048)
    const uint2* h1v = (const uint2*)lds;            // rows [0,1024) (over dead x)
    const uint2* h2v = (const uint2*)(lds + 16384);  // rows [0,2048) (over dead h0)
    uint2* const h0w = (uint2*)(lds + 16384);
    uint2* const h1w = (uint2*)lds;
    uint4* const xlw = (uint4*)lds;                  // 2 rows per uint4

    // ---- stage tile0 x: 4x dwordx4 -> transpose -> 2x ds_write_b128 ----
    {
        const float4 v0 = *(const float4*)(x + (size_t)(b0 + 0) * 4096 + j0);
        const float4 v1 = *(const float4*)(x + (size_t)(b0 + 1) * 4096 + j0);
        const float4 v2 = *(const float4*)(x + (size_t)(b0 + 2) * 4096 + j0);
        const float4 v3 = *(const float4*)(x + (size_t)(b0 + 3) * 4096 + j0);
        xlw[t * 2]     = uint4{packh2(v0.x, v1.x), packh2(v2.x, v3.x),
                               packh2(v0.y, v1.y), packh2(v2.y, v3.y)};
        xlw[t * 2 + 1] = uint4{packh2(v0.z, v1.z), packh2(v2.z, v3.z),
                               packh2(v0.w, v1.w), packh2(v2.w, v3.w)};
    }
    __syncthreads();

    unsigned pre[8];
#pragma unroll 1
    for (int tile = 0; tile < 2; ++tile) {
        const int bb = b0 + (tile << 2);
        const bool dopre = (tile == 0);

        // ---- L0: 4096 -> 2048, o = 2t, 2t+1 ----
#pragma unroll
        for (int k = 0; k < 2; ++k) {
            const int o = 2 * t + k;
            h0w[o] = raw_bits(gate(xl, idx0, w0, train, o));
        }
        __syncthreads();

        // ---- L1: 2048 -> 1024, o = t; issue tile1's x loads first (latency
        //      covered by the gate), pack to 8 VGPRs after ----
        float4 p0, p1, p2, p3;
        if (dopre) {
            p0 = *(const float4*)(x + (size_t)(b0 + 4) * 4096 + j0);
            p1 = *(const float4*)(x + (size_t)(b0 + 5) * 4096 + j0);
            p2 = *(const float4*)(x + (size_t)(b0 + 6) * 4096 + j0);
            p3 = *(const float4*)(x + (size_t)(b0 + 7) * 4096 + j0);
        }
        h1w[t] = raw_bits(gate(h0v, idx1, w1, train, t));
        if (dopre) {
            pre[0] = packh2(p0.x, p1.x); pre[1] = packh2(p2.x, p3.x);
            pre[2] = packh2(p0.y, p1.y); pre[3] = packh2(p2.y, p3.y);
            pre[4] = packh2(p0.z, p1.z); pre[5] = packh2(p2.z, p3.z);
            pre[6] = packh2(p0.w, p1.w); pre[7] = packh2(p2.w, p3.w);
        }
        __syncthreads();

        // ---- L2: 1024 -> 2048, o = 2t, 2t+1 ----
#pragma unroll
        for (int k = 0; k < 2; ++k) {
            const int o = 2 * t + k;
            h0w[o] = raw_bits(gate(h1v, idx2, w2, train, o));   // h2 over dead h0
        }
        __syncthreads();

        // ---- L3: 2048 -> 4096, o = 4t..4t+3; first drop tile1's x into the
        //      now-dead x buffer, then gates + float4 stores ----
        if (dopre) {
            xlw[t * 2]     = uint4{pre[0], pre[1], pre[2], pre[3]};
            xlw[t * 2 + 1] = uint4{pre[4], pre[5], pre[6], pre[7]};
        }
        {
            Raw r0 = gate(h2v, idx3, w3, train, 4 * t);
            Raw r1 = gate(h2v, idx3, w3, train, 4 * t + 1);
            Raw r2 = gate(h2v, idx3, w3, train, 4 * t + 2);
            Raw r3 = gate(h2v, idx3, w3, train, 4 * t + 3);
            float4 o4;
            o4 = make_float4((float)r0.lo[0], (float)r1.lo[0], (float)r2.lo[0], (float)r3.lo[0]);
            *(float4*)(out + (size_t)(bb + 0) * 4096 + j0) = o4;
            o4 = make_float4((float)r0.lo[1], (float)r1.lo[1], (float)r2.lo[1], (float)r3.lo[1]);
            *(float4*)(out + (size_t)(bb + 1) * 4096 + j0) = o4;
            o4 = make_float4((float)r0.hi[0], (float)r1.hi[0], (float)r2.hi[0], (float)r3.hi[0]);
            *(float4*)(out + (size_t)(bb + 2) * 4096 + j0) = o4;
            o4 = make_float4((float)r0.hi[1], (float)r1.hi[1], (float)r2.hi[1], (float)r3.hi[1]);
            *(float4*)(out + (size_t)(bb + 3) * 4096 + j0) = o4;
        }
        __syncthreads();
    }
}

extern "C" void kernel_launch(void* const* d_in, const int* in_sizes, int n_in,
                              void* d_out, int out_size, void* d_ws, size_t ws_size,
                              hipStream_t stream) {
    const float* x        = (const float*)d_in[0];
    const float* w0       = (const float*)d_in[1];
    const float* w1       = (const float*)d_in[2];
    const float* w2       = (const float*)d_in[3];
    const float* w3       = (const float*)d_in[4];
    const int4*  idx0     = (const int4*)d_in[5];
    const int4*  idx1     = (const int4*)d_in[6];
    const int4*  idx2     = (const int4*)d_in[7];
    const int4*  idx3     = (const int4*)d_in[8];
    const int*   is_train = (const int*)d_in[9];
    float*       out      = (float*)d_out;

    (void)d_ws; (void)ws_size;  // no workspace

    ddlg_fused<<<512, 1024, 0, stream>>>(x, w0, w1, w2, w3, is_train,
                                         idx0, idx1, idx2, idx3, out);
}

// Round 7
// 167.191 us; speedup vs baseline: 2.1062x; 2.1062x over previous
//
#include <hip/hip_runtime.h>

// DDLG autoencoder, fused, batch-tile 2, 512-thr blocks, 4 blocks/CU.
//   out[b][o] = sum_f prob[o][f] * op_f(x[b][idx[o][0..7]])
// R1: divide-free Einstein reductions via homomorphisms:
//     ein-product = 2D/(N+D),  D=prod(f), N=prod(2-f)
//     ein-sum     = (N-D)/(N+D), N=prod(1+f), D=prod(1-f)
// R8: combined-denominator finale (one rcp pair per h2 over s1*s2; range
//     proof: s1*s2 <= 2.25^8 + 257 ~ 914 < 65504, numerators <= 912).
// R9: chain+finale in explicit 2-wide _Float16 (native v_pk_*_f16 width).
// R13 (this round) -- R6's persistent prefetch spilled to scratch (FETCH
//     304 MB / WRITE 450 MB = spill traffic); reverted. New axis: R5 showed
//     "decoupled barriers" only ever ran at 24 waves/CU; this tests
//     decoupling AT FULL 32-wave residency:
//   - batch-tile 2, 512-thr blocks, 24 KB LDS -> 4 blocks/CU (32 waves).
//     Barriers couple 8 waves (was 16); 4 resident blocks at independent
//     phases cover each other's barrier drains and gather latency.
//   - prep_k/probsH restored (softmax VALU out of the hot kernel; R5
//     measured it at ~+10 us VALU-busy when inlined).
//   - one LDS row = 2 fp16 (4 B, ds_read_b32 gathers, 2-way bank alias
//     at stride-1 staging = free per m136).
//     LDS overlays (uint rows): x @ [0,4096) | h0 @ [4096,6144) |
//     h1 @ [0,1024) over dead x | h2 @ [4096,6144) over dead h0.

typedef _Float16 h2 __attribute__((ext_vector_type(2)));
typedef _Float16 h4 __attribute__((ext_vector_type(4)));

__device__ __forceinline__ float fastrcp(float x) { return __builtin_amdgcn_rcpf(x); }
__device__ __forceinline__ _Float16 hrcp(_Float16 x) {
#if __has_builtin(__builtin_amdgcn_rcph)
    return __builtin_amdgcn_rcph(x);
#else
    return (_Float16)__builtin_amdgcn_rcpf((float)x);
#endif
}
__device__ __forceinline__ h2 splat2(_Float16 s) { h2 v = {s, s}; return v; }
__device__ __forceinline__ unsigned packh2(float a, float b) {
    h2 v = {(_Float16)a, (_Float16)b};
    return __builtin_bit_cast(unsigned, v);
}

// ---------------- prep: fp16 prob table only ----------------
// probsH: [0,2048) L0 | [2048,3072) L1 | [3072,5120) L2 | [5120,9216) L3
__global__ __launch_bounds__(256) void prep_k(const float* __restrict__ w0,
                                              const float* __restrict__ w1,
                                              const float* __restrict__ w2,
                                              const float* __restrict__ w3,
                                              const int* __restrict__ is_train,
                                              h4* __restrict__ probsH) {
    const int g = blockIdx.x * 256 + threadIdx.x;   // grid 36 -> 9216 exact
    const float* w; int o;
    if (g < 2048)      { w = w0; o = g; }
    else if (g < 3072) { w = w1; o = g - 2048; }
    else if (g < 5120) { w = w2; o = g - 3072; }
    else               { w = w3; o = g - 5120; }
    float wv[4];
#pragma unroll
    for (int c = 0; c < 4; ++c) wv[c] = w[(o << 2) + c];
    float p[4];
    if (*is_train) {
        float m = fmaxf(fmaxf(wv[0], wv[1]), fmaxf(wv[2], wv[3]));
        float s = 0.0f;
#pragma unroll
        for (int c = 0; c < 4; ++c) { p[c] = __expf(wv[c] - m); s += p[c]; }
        float inv = fastrcp(s);
#pragma unroll
        for (int c = 0; c < 4; ++c) p[c] *= inv;
    } else {
        int a = 0; float best = wv[0];
#pragma unroll
        for (int c = 1; c < 4; ++c) if (wv[c] > best) { best = wv[c]; a = c; }
#pragma unroll
        for (int c = 0; c < 4; ++c) p[c] = (c == a) ? 1.0f : 0.0f;
    }
    probsH[g] = h4{(_Float16)p[0], (_Float16)p[1], (_Float16)p[2], (_Float16)p[3]};
}

// ---------------- chain state: 6 parallel reductions, one h2 (2 batch lanes) ----
struct Chain { h2 mn, mx, De, Ne, Nc, Dc; };

__device__ __forceinline__ h2 row_at(const unsigned* __restrict__ rows, int i) {
    return __builtin_bit_cast(h2, rows[i]);        // one ds_read_b32
}
__device__ __forceinline__ void cinit(Chain& C, h2 v) {
    const h2 one = splat2((_Float16)1.0f), two = splat2((_Float16)2.0f);
    C.mn = v; C.mx = v; C.De = v;
    C.Ne = two - v; C.Nc = one + v; C.Dc = one - v;
}
__device__ __forceinline__ void cstep(Chain& C, h2 v) {
    const h2 two = splat2((_Float16)2.0f);
    C.mn = __builtin_elementwise_min(C.mn, v);
    C.mx = __builtin_elementwise_max(C.mx, v);
    C.De *= v;
    C.Ne *= (two - v);
    C.Nc += C.Nc * v;   // pk_fma: Nc *= (1+v)
    C.Dc -= C.Dc * v;   // pk_fma: Dc *= (1-v)
}
// combined-denominator finale: one rcp pair serves both ein and coe.
__device__ __forceinline__ h2 finale(const Chain& C, h4 P) {
    h2 s1 = C.Ne + C.De;        // [1, 257]
    h2 s2 = C.Nc + C.Dc;        // [1, 257]
    h2 d1 = C.Nc - C.Dc;        // [0, 256]
    h2 ss = s1 * s2;            // <= ~914: fp16-safe
    h2 r  = {hrcp(ss[0]), hrcp(ss[1])};
    h2 t1 = (C.De + C.De) * s2; // <= 514
    h2 t2 = d1 * s1;            // <= 912
    h2 num = splat2(P[2]) * t1 + splat2(P[3]) * t2;
    return splat2(P[0]) * C.mn + splat2(P[1]) * C.mx + num * r;
}

// ---------------- one gate, 2 batch lanes ----------------
__device__ __forceinline__ h2 gate(const unsigned* __restrict__ rows,
                                   const int4* __restrict__ idx,
                                   const h4* __restrict__ probs, int o) {
    const int4 i0 = idx[o * 2], i1 = idx[o * 2 + 1];
    const h4 P = probs[o];
    h2 A[8];
    A[0] = row_at(rows, i0.x); A[1] = row_at(rows, i0.y);
    A[2] = row_at(rows, i0.z); A[3] = row_at(rows, i0.w);
    A[4] = row_at(rows, i1.x); A[5] = row_at(rows, i1.y);
    A[6] = row_at(rows, i1.z); A[7] = row_at(rows, i1.w);
    Chain C; cinit(C, A[0]);
#pragma unroll
    for (int c = 1; c < 8; ++c) cstep(C, A[c]);
    return finale(C, P);
}

// ---------------- the fused network ----------------
// grid = 2048 (one block per 2-batch tile), block = 512, 24 KB LDS,
// 4 blocks/CU = 32 waves; barriers couple only 8 waves.
__global__ __launch_bounds__(512, 8) void ddlg_fused(const float* __restrict__ x,
                                                     const h4* __restrict__ probsH,
                                                     const int4* __restrict__ idx0,
                                                     const int4* __restrict__ idx1,
                                                     const int4* __restrict__ idx2,
                                                     const int4* __restrict__ idx3,
                                                     float* __restrict__ out) {
    __shared__ __align__(16) unsigned lds[6144];    // 24 KB, rows of 2 fp16
    const int t  = threadIdx.x;
    const int b0 = blockIdx.x << 1;

    const unsigned* xl  = lds;           // rows [0,4096)
    const unsigned* h0v = lds + 4096;    // rows [0,2048)
    const unsigned* h1v = lds;           // rows [0,1024) (over dead x)
    const unsigned* h2v = lds + 4096;    // rows [0,2048) (over dead h0)

    // ---- stage x: thread owns rows j = t + 512c; 2 coalesced loads -> b32 ----
#pragma unroll
    for (int c = 0; c < 8; ++c) {
        const int j = (c << 9) + t;
        const float v0 = x[(size_t)(b0 + 0) * 4096 + j];
        const float v1 = x[(size_t)(b0 + 1) * 4096 + j];
        lds[j] = packh2(v0, v1);         // stride-1 ds_write_b32: conflict-free
    }
    __syncthreads();

    // ---- L0: 4096 -> 2048, o = t + 512k, k=0..3 ----
#pragma unroll
    for (int k = 0; k < 4; ++k) {
        const int o = (k << 9) + t;
        h2 r = gate(xl, idx0, probsH, o);
        lds[4096 + o] = __builtin_bit_cast(unsigned, r);
    }
    __syncthreads();

    // ---- L1: 2048 -> 1024, o = t + 512k, k=0..1 ----
#pragma unroll
    for (int k = 0; k < 2; ++k) {
        const int o = (k << 9) + t;
        h2 r = gate(h0v, idx1, probsH + 2048, o);
        lds[o] = __builtin_bit_cast(unsigned, r);
    }
    __syncthreads();

    // ---- L2: 1024 -> 2048, o = t + 512k, k=0..3 ----
#pragma unroll
    for (int k = 0; k < 4; ++k) {
        const int o = (k << 9) + t;
        h2 r = gate(h1v, idx2, probsH + 3072, o);
        lds[4096 + o] = __builtin_bit_cast(unsigned, r);
    }
    __syncthreads();

    // ---- L3: 2048 -> 4096, o = t + 512k, k=0..7; coalesced dword stores ----
#pragma unroll
    for (int k = 0; k < 8; ++k) {
        const int o = (k << 9) + t;
        h2 r = gate(h2v, idx3, probsH + 5120, o);
        out[(size_t)(b0 + 0) * 4096 + o] = (float)r[0];
        out[(size_t)(b0 + 1) * 4096 + o] = (float)r[1];
    }
}

extern "C" void kernel_launch(void* const* d_in, const int* in_sizes, int n_in,
                              void* d_out, int out_size, void* d_ws, size_t ws_size,
                              hipStream_t stream) {
    const float* x        = (const float*)d_in[0];
    const float* w0       = (const float*)d_in[1];
    const float* w1       = (const float*)d_in[2];
    const float* w2       = (const float*)d_in[3];
    const float* w3       = (const float*)d_in[4];
    const int4*  idx0     = (const int4*)d_in[5];
    const int4*  idx1     = (const int4*)d_in[6];
    const int4*  idx2     = (const int4*)d_in[7];
    const int4*  idx3     = (const int4*)d_in[8];
    const int*   is_train = (const int*)d_in[9];
    float*       out      = (float*)d_out;

    // ws: probsH 9216*8B = 72 KB @0
    h4* probsH = (h4*)d_ws;

    prep_k<<<36, 256, 0, stream>>>(w0, w1, w2, w3, is_train, probsH);
    ddlg_fused<<<2048, 512, 0, stream>>>(x, probsH, idx0, idx1, idx2, idx3, out);
}

// Round 8
// 160.888 us; speedup vs baseline: 2.1887x; 1.0392x over previous
//
#include <hip/hip_runtime.h>

// DDLG autoencoder, fully fused, batch-tile 4, fp16 packed compute.
//   out[b][o] = sum_f prob[o][f] * op_f(x[b][idx[o][0..7]])
// R1: divide-free Einstein reductions via homomorphisms:
//     ein-product = 2D/(N+D),  D=prod(f), N=prod(2-f)
//     ein-sum     = (N-D)/(N+D), N=prod(1+f), D=prod(1-f)
// R5: 48 KB LDS, 1024-thr blocks, 2 blocks/CU (the measured-best residency;
//     every other structure R4-R7 was equal or worse).
// R8: combined-denominator finale (one rcp pair per h2 over s1*s2; range
//     proof: s1*s2 <= 2.25^8 + 257 ~ 914 < 65504, numerators <= 912).
// R14 (this round): chain init/step emitted as EXPLICIT VOP3P inline asm
//     (v_pk_min/max/mul/add/fma_f16, neg modifiers for subs). Cycle audit:
//     measured VALU-busy (~95K cy/SIMD) = exactly 2x the ideal packed inst
//     count (~46K); R4 proved per-gate fixed VALU ~ 0, so the 2x must be the
//     chain ops scalarizing to v_*_f16 pairs -- which also re-explains R3's
//     null (h4 AND h2 both scalarize; that test couldn't distinguish).
//     Inline asm guarantees 1 pk inst per 2 lanes. Finale stays C++.
//     LDS overlays (fp16 rows of 4 = 8 B, ds_read_b64 gathers):
//       x @ [0,16384) | h0 @ [16384,24576) | h1 @ [0,4096) | h2 @ [16384,24576)

typedef _Float16 h2 __attribute__((ext_vector_type(2)));
typedef _Float16 h4 __attribute__((ext_vector_type(4)));

__device__ __forceinline__ float fastrcp(float x) { return __builtin_amdgcn_rcpf(x); }
__device__ __forceinline__ _Float16 hrcp(_Float16 x) {
#if __has_builtin(__builtin_amdgcn_rcph)
    return __builtin_amdgcn_rcph(x);
#else
    return (_Float16)__builtin_amdgcn_rcpf((float)x);
#endif
}
__device__ __forceinline__ h2 splat2(_Float16 s) { h2 v = {s, s}; return v; }
__device__ __forceinline__ unsigned packh2(float a, float b) {
    h2 v = {(_Float16)a, (_Float16)b};
    return __builtin_bit_cast(unsigned, v);
}

// ---------------- forced VOP3P packed-fp16 ops (2 elems / 1 inst) ----------------
__device__ __forceinline__ unsigned pk_min(unsigned a, unsigned b) {
    unsigned d; asm("v_pk_min_f16 %0, %1, %2" : "=v"(d) : "v"(a), "v"(b)); return d;
}
__device__ __forceinline__ unsigned pk_max(unsigned a, unsigned b) {
    unsigned d; asm("v_pk_max_f16 %0, %1, %2" : "=v"(d) : "v"(a), "v"(b)); return d;
}
__device__ __forceinline__ unsigned pk_mul(unsigned a, unsigned b) {
    unsigned d; asm("v_pk_mul_f16 %0, %1, %2" : "=v"(d) : "v"(a), "v"(b)); return d;
}
__device__ __forceinline__ unsigned pk_add(unsigned a, unsigned b) {
    unsigned d; asm("v_pk_add_f16 %0, %1, %2" : "=v"(d) : "v"(a), "v"(b)); return d;
}
__device__ __forceinline__ unsigned pk_sub(unsigned a, unsigned b) {   // a - b
    unsigned d;
    asm("v_pk_add_f16 %0, %1, %2 neg_lo:[0,1] neg_hi:[0,1]" : "=v"(d) : "v"(a), "v"(b));
    return d;
}
__device__ __forceinline__ unsigned pk_fma(unsigned a, unsigned b, unsigned c) { // a*b+c
    unsigned d;
    asm("v_pk_fma_f16 %0, %1, %2, %3" : "=v"(d) : "v"(a), "v"(b), "v"(c));
    return d;
}
__device__ __forceinline__ unsigned pk_fnma(unsigned a, unsigned b, unsigned c) { // c-a*b
    unsigned d;
    asm("v_pk_fma_f16 %0, %1, %2, %3 neg_lo:[1,0,0] neg_hi:[1,0,0]"
        : "=v"(d) : "v"(a), "v"(b), "v"(c));
    return d;
}

#define PK_ONE 0x3C003C00u   // {1.0h, 1.0h}
#define PK_TWO 0x40004000u   // {2.0h, 2.0h}

// ---------------- prep: fp16 prob table only ----------------
// probsH: [0,2048) L0 | [2048,3072) L1 | [3072,5120) L2 | [5120,9216) L3
__global__ __launch_bounds__(256) void prep_k(const float* __restrict__ w0,
                                              const float* __restrict__ w1,
                                              const float* __restrict__ w2,
                                              const float* __restrict__ w3,
                                              const int* __restrict__ is_train,
                                              h4* __restrict__ probsH) {
    const int g = blockIdx.x * 256 + threadIdx.x;   // grid 36 -> 9216 exact
    const float* w; int o;
    if (g < 2048)      { w = w0; o = g; }
    else if (g < 3072) { w = w1; o = g - 2048; }
    else if (g < 5120) { w = w2; o = g - 3072; }
    else               { w = w3; o = g - 5120; }
    float wv[4];
#pragma unroll
    for (int c = 0; c < 4; ++c) wv[c] = w[(o << 2) + c];
    float p[4];
    if (*is_train) {
        float m = fmaxf(fmaxf(wv[0], wv[1]), fmaxf(wv[2], wv[3]));
        float s = 0.0f;
#pragma unroll
        for (int c = 0; c < 4; ++c) { p[c] = __expf(wv[c] - m); s += p[c]; }
        float inv = fastrcp(s);
#pragma unroll
        for (int c = 0; c < 4; ++c) p[c] *= inv;
    } else {
        int a = 0; float best = wv[0];
#pragma unroll
        for (int c = 1; c < 4; ++c) if (wv[c] > best) { best = wv[c]; a = c; }
#pragma unroll
        for (int c = 0; c < 4; ++c) p[c] = (c == a) ? 1.0f : 0.0f;
    }
    probsH[g] = h4{(_Float16)p[0], (_Float16)p[1], (_Float16)p[2], (_Float16)p[3]};
}

// ---------------- chain state: 6 reductions x 2 packed halves, in uint bits ----
struct Chain { unsigned mn0, mn1, mx0, mx1, De0, De1, Ne0, Ne1, Nc0, Nc1, Dc0, Dc1; };

__device__ __forceinline__ void cinit(Chain& C, uint2 v) {
    C.mn0 = v.x; C.mx0 = v.x; C.De0 = v.x;
    C.Ne0 = pk_sub(PK_TWO, v.x); C.Nc0 = pk_add(PK_ONE, v.x); C.Dc0 = pk_sub(PK_ONE, v.x);
    C.mn1 = v.y; C.mx1 = v.y; C.De1 = v.y;
    C.Ne1 = pk_sub(PK_TWO, v.y); C.Nc1 = pk_add(PK_ONE, v.y); C.Dc1 = pk_sub(PK_ONE, v.y);
}
__device__ __forceinline__ void cstep(Chain& C, uint2 v) {
    C.mn0 = pk_min(C.mn0, v.x);            C.mn1 = pk_min(C.mn1, v.y);
    C.mx0 = pk_max(C.mx0, v.x);            C.mx1 = pk_max(C.mx1, v.y);
    C.De0 = pk_mul(C.De0, v.x);            C.De1 = pk_mul(C.De1, v.y);
    const unsigned w0 = pk_sub(PK_TWO, v.x), w1 = pk_sub(PK_TWO, v.y);
    C.Ne0 = pk_mul(C.Ne0, w0);             C.Ne1 = pk_mul(C.Ne1, w1);
    C.Nc0 = pk_fma(C.Nc0, v.x, C.Nc0);     C.Nc1 = pk_fma(C.Nc1, v.y, C.Nc1);   // *= (1+v)
    C.Dc0 = pk_fnma(C.Dc0, v.x, C.Dc0);    C.Dc1 = pk_fnma(C.Dc1, v.y, C.Dc1);  // *= (1-v)
}

__device__ __forceinline__ h2 ash2(unsigned u) { return __builtin_bit_cast(h2, u); }

// combined-denominator finale (C++; small vs chain): one rcp pair per half.
__device__ __forceinline__ uint2 finale(const Chain& C, h4 P) {
    h2 s10 = ash2(C.Ne0) + ash2(C.De0), s11 = ash2(C.Ne1) + ash2(C.De1); // [1,257]
    h2 s20 = ash2(C.Nc0) + ash2(C.Dc0), s21 = ash2(C.Nc1) + ash2(C.Dc1); // [1,257]
    h2 d10 = ash2(C.Nc0) - ash2(C.Dc0), d11 = ash2(C.Nc1) - ash2(C.Dc1); // [0,256]
    h2 ss0 = s10 * s20,                 ss1 = s11 * s21;                 // <= ~914
    h2 r0 = {hrcp(ss0[0]), hrcp(ss0[1])};
    h2 r1 = {hrcp(ss1[0]), hrcp(ss1[1])};
    h2 t10 = (ash2(C.De0) + ash2(C.De0)) * s20;   // <= 514
    h2 t11 = (ash2(C.De1) + ash2(C.De1)) * s21;
    h2 t20 = d10 * s10, t21 = d11 * s11;          // <= 912
    const h2 P0 = splat2(P[0]), P1 = splat2(P[1]);
    const h2 P2 = splat2(P[2]), P3 = splat2(P[3]);
    h2 num0 = P2 * t10 + P3 * t20;
    h2 num1 = P2 * t11 + P3 * t21;
    h2 lo = P0 * ash2(C.mn0) + P1 * ash2(C.mx0) + num0 * r0;
    h2 hi = P0 * ash2(C.mn1) + P1 * ash2(C.mx1) + num1 * r1;
    return uint2{__builtin_bit_cast(unsigned, lo), __builtin_bit_cast(unsigned, hi)};
}

// ---------------- one gate, 4 batch lanes ----------------
__device__ __forceinline__ uint2 gate(const uint2* __restrict__ rows,
                                      const int4* __restrict__ idx,
                                      const h4* __restrict__ probs, int o) {
    const int4 i0 = idx[o * 2], i1 = idx[o * 2 + 1];
    const h4 P = probs[o];
    uint2 A[8];
    A[0] = rows[i0.x]; A[1] = rows[i0.y]; A[2] = rows[i0.z]; A[3] = rows[i0.w];
    A[4] = rows[i1.x]; A[5] = rows[i1.y]; A[6] = rows[i1.z]; A[7] = rows[i1.w];
    Chain C; cinit(C, A[0]);
#pragma unroll
    for (int c = 1; c < 8; ++c) cstep(C, A[c]);
    return finale(C, P);
}

// ---------------- the fused network ----------------
// grid = 1024 (one block per 4-batch tile), block = 1024, 48 KB, 2 blocks/CU
__global__ __launch_bounds__(1024, 8) void ddlg_fused(const float* __restrict__ x,
                                                      const h4* __restrict__ probsH,
                                                      const int4* __restrict__ idx0,
                                                      const int4* __restrict__ idx1,
                                                      const int4* __restrict__ idx2,
                                                      const int4* __restrict__ idx3,
                                                      float* __restrict__ out) {
    __shared__ __align__(16) _Float16 lds[24576];   // 48 KB
    const int t  = threadIdx.x;
    const int b0 = blockIdx.x << 2;

    const uint2* xl  = (const uint2*)lds;            // rows [0,4096)
    const uint2* h0v = (const uint2*)(lds + 16384);  // rows [0,2048)
    const uint2* h1v = (const uint2*)lds;            // rows [0,1024) (over dead x)
    const uint2* h2v = (const uint2*)(lds + 16384);  // rows [0,2048) (over dead h0)
    uint2* const h0w = (uint2*)(lds + 16384);
    uint2* const h1w = (uint2*)lds;

    // ---- stage x: thread owns rows j = t + 1024c; 4 coalesced loads -> b64 ----
#pragma unroll
    for (int c = 0; c < 4; ++c) {
        const int j = (c << 10) + t;
        const float v0 = x[(size_t)(b0 + 0) * 4096 + j];
        const float v1 = x[(size_t)(b0 + 1) * 4096 + j];
        const float v2 = x[(size_t)(b0 + 2) * 4096 + j];
        const float v3 = x[(size_t)(b0 + 3) * 4096 + j];
        ((uint2*)lds)[j] = uint2{packh2(v0, v1), packh2(v2, v3)};
    }
    __syncthreads();

    // ---- L0: 4096 -> 2048, o = t, t+1024 ----
#pragma unroll
    for (int k = 0; k < 2; ++k) {
        const int o = (k << 10) + t;
        h0w[o] = gate(xl, idx0, probsH, o);
    }
    __syncthreads();

    // ---- L1: 2048 -> 1024, o = t ----
    h1w[t] = gate(h0v, idx1, probsH + 2048, t);
    __syncthreads();

    // ---- L2: 1024 -> 2048, o = t, t+1024 ----
#pragma unroll
    for (int k = 0; k < 2; ++k) {
        const int o = (k << 10) + t;
        h0w[o] = gate(h1v, idx2, probsH + 3072, o);   // h2 over dead h0
    }
    __syncthreads();

    // ---- L3: 2048 -> 4096, o = t + 1024k; coalesced dword stores ----
#pragma unroll
    for (int k = 0; k < 4; ++k) {
        const int o = (k << 10) + t;
        uint2 r = gate(h2v, idx3, probsH + 5120, o);
        h2 lo = ash2(r.x), hi = ash2(r.y);
        out[(size_t)(b0 + 0) * 4096 + o] = (float)lo[0];
        out[(size_t)(b0 + 1) * 4096 + o] = (float)lo[1];
        out[(size_t)(b0 + 2) * 4096 + o] = (float)hi[0];
        out[(size_t)(b0 + 3) * 4096 + o] = (float)hi[1];
    }
}

extern "C" void kernel_launch(void* const* d_in, const int* in_sizes, int n_in,
                              void* d_out, int out_size, void* d_ws, size_t ws_size,
                              hipStream_t stream) {
    const float* x        = (const float*)d_in[0];
    const float* w0       = (const float*)d_in[1];
    const float* w1       = (const float*)d_in[2];
    const float* w2       = (const float*)d_in[3];
    const float* w3       = (const float*)d_in[4];
    const int4*  idx0     = (const int4*)d_in[5];
    const int4*  idx1     = (const int4*)d_in[6];
    const int4*  idx2     = (const int4*)d_in[7];
    const int4*  idx3     = (const int4*)d_in[8];
    const int*   is_train = (const int*)d_in[9];
    float*       out      = (float*)d_out;

    // ws: probsH 9216*8B = 72 KB @0
    h4* probsH = (h4*)d_ws;

    prep_k<<<36, 256, 0, stream>>>(w0, w1, w2, w3, is_train, probsH);
    ddlg_fused<<<1024, 1024, 0, stream>>>(x, probsH, idx0, idx1, idx2, idx3, out);
}